// Round 1
// baseline (66.344 us; speedup 1.0000x reference)
//
#include <hip/hip_runtime.h>

// SVD++ scoring: out[b] = mu + b_u + b_i + q_i . (p_u + rsqrt(len)*sum_{l<len} y[hist[b][l]])
// B=8192, D=128, L=200. One 64-lane wave per batch element; two 32-lane halves
// each gather one implicit row per step (float4/lane = 512B coalesced row read).

#define BB 8192
#define DD 128
#define LL 200

__global__ __launch_bounds__(256) void svdpp_kernel(
    const int* __restrict__ user_ids,
    const int* __restrict__ item_ids,
    const int* __restrict__ hist_items,
    const int* __restrict__ hist_len,
    const float* __restrict__ user_emb,
    const float* __restrict__ item_emb,
    const float* __restrict__ implicit_emb,
    const float* __restrict__ user_bias,
    const float* __restrict__ item_bias,
    const float* __restrict__ global_bias,
    float* __restrict__ out)
{
    const int wid  = (blockIdx.x * blockDim.x + threadIdx.x) >> 6;  // one wave per batch elem
    if (wid >= BB) return;
    const int lane = threadIdx.x & 63;
    const int half = lane >> 5;          // 0: even history slots, 1: odd history slots
    const int d0   = (lane & 31) << 2;   // 4 floats per lane covers D=128 with 32 lanes

    const int b   = wid;
    const int len = hist_len[b];
    const int u   = user_ids[b];
    const int it  = item_ids[b];

    const int* __restrict__ hrow = hist_items + (size_t)b * LL;

    float4 acc = make_float4(0.f, 0.f, 0.f, 0.f);

    // Each half strides by 2 through the history; unroll 2 -> 4 row loads in flight/wave.
    int l = half;
    for (; l + 2 < len; l += 4) {
        const int j0 = hrow[l];
        const int j1 = hrow[l + 2];
        const float4 y0 = *reinterpret_cast<const float4*>(implicit_emb + (size_t)j0 * DD + d0);
        const float4 y1 = *reinterpret_cast<const float4*>(implicit_emb + (size_t)j1 * DD + d0);
        acc.x += y0.x; acc.y += y0.y; acc.z += y0.z; acc.w += y0.w;
        acc.x += y1.x; acc.y += y1.y; acc.z += y1.z; acc.w += y1.w;
    }
    if (l < len) {
        const int j = hrow[l];
        const float4 y = *reinterpret_cast<const float4*>(implicit_emb + (size_t)j * DD + d0);
        acc.x += y.x; acc.y += y.y; acc.z += y.z; acc.w += y.w;
    }

    // Merge the two parity halves: lane and lane^32 hold partials for the SAME d-range.
    acc.x += __shfl_xor(acc.x, 32, 64);
    acc.y += __shfl_xor(acc.y, 32, 64);
    acc.z += __shfl_xor(acc.z, 32, 64);
    acc.w += __shfl_xor(acc.w, 32, 64);

    const float norm = (len > 0) ? rsqrtf((float)len) : 0.f;
    const float4 p = *reinterpret_cast<const float4*>(user_emb + (size_t)u * DD + d0);
    const float4 q = *reinterpret_cast<const float4*>(item_emb + (size_t)it * DD + d0);

    float dot = (p.x + norm * acc.x) * q.x
              + (p.y + norm * acc.y) * q.y
              + (p.z + norm * acc.z) * q.z
              + (p.w + norm * acc.w) * q.w;

    // Reduce the 32 distinct lanes (0..31) into lane 0. (lane i and i+32 are duplicates.)
    dot += __shfl_down(dot, 16, 64);
    dot += __shfl_down(dot, 8, 64);
    dot += __shfl_down(dot, 4, 64);
    dot += __shfl_down(dot, 2, 64);
    dot += __shfl_down(dot, 1, 64);

    if (lane == 0) {
        out[b] = global_bias[0] + user_bias[u] + item_bias[it] + dot;
    }
}

extern "C" void kernel_launch(void* const* d_in, const int* in_sizes, int n_in,
                              void* d_out, int out_size, void* d_ws, size_t ws_size,
                              hipStream_t stream) {
    const int*   user_ids     = (const int*)d_in[0];
    const int*   item_ids     = (const int*)d_in[1];
    const int*   hist_items   = (const int*)d_in[2];
    const int*   hist_len     = (const int*)d_in[3];
    const float* user_emb     = (const float*)d_in[4];
    const float* item_emb     = (const float*)d_in[5];
    const float* implicit_emb = (const float*)d_in[6];
    const float* user_bias    = (const float*)d_in[7];
    const float* item_bias    = (const float*)d_in[8];
    const float* global_bias  = (const float*)d_in[9];
    float* out = (float*)d_out;

    // One wave per batch element: 8192 waves -> 2048 blocks of 256 threads.
    const int threads = 256;
    const int blocks  = (BB * 64) / threads;
    svdpp_kernel<<<blocks, threads, 0, stream>>>(
        user_ids, item_ids, hist_items, hist_len,
        user_emb, item_emb, implicit_emb,
        user_bias, item_bias, global_bias, out);
}

// Round 2
// 63.973 us; speedup vs baseline: 1.0371x; 1.0371x over previous
//
#include <hip/hip_runtime.h>

// SVD++ scoring: out[b] = mu + b_u + b_i + q_i . (p_u + rsqrt(len)*sum_{l<len} y[hist[b][l]])
// B=8192, D=128, L=200.
//
// Round 2 structure: ONE BLOCK (256 thr = 4 waves = 8 half-waves) PER BATCH ELEMENT.
// The 8 half-waves stride the history by 8, so intra-block work is balanced to
// len/8 rows per half-wave regardless of len; inter-block imbalance is handled by
// dynamic block scheduling (8192 blocks, 8 resident/CU, backfilled as they finish).
// Uses q.(sum y) == sum(q.y) so each wave reduces to one scalar; 16B LDS combine.

#define BB 8192
#define DD 128
#define LL 200

__global__ __launch_bounds__(256) void svdpp_kernel(
    const int* __restrict__ user_ids,
    const int* __restrict__ item_ids,
    const int* __restrict__ hist_items,
    const int* __restrict__ hist_len,
    const float* __restrict__ user_emb,
    const float* __restrict__ item_emb,
    const float* __restrict__ implicit_emb,
    const float* __restrict__ user_bias,
    const float* __restrict__ item_bias,
    const float* __restrict__ global_bias,
    float* __restrict__ out)
{
    const int b    = blockIdx.x;          // one block per batch element
    const int tid  = threadIdx.x;
    const int w    = tid >> 6;            // wave 0..3
    const int lane = tid & 63;
    const int half = lane >> 5;           // two 32-lane halves per wave
    const int sub  = (w << 1) | half;     // 8 half-wave work units, stride 8
    const int d0   = (lane & 31) << 2;    // 4 floats/lane covers D=128 with 32 lanes

    const int len = hist_len[b];          // uniform -> scalar loads
    const int it  = item_ids[b];

    const float4 q = *reinterpret_cast<const float4*>(item_emb + (size_t)it * DD + d0);
    const int* __restrict__ hrow = hist_items + (size_t)b * LL;

    float4 acc = make_float4(0.f, 0.f, 0.f, 0.f);

    // half-wave `sub` handles slots sub, sub+8, sub+16, ... ; unroll 2.
    int l = sub;
    for (; l + 8 < len; l += 16) {
        const int j0 = hrow[l];
        const int j1 = hrow[l + 8];
        const float4 y0 = *reinterpret_cast<const float4*>(implicit_emb + (size_t)j0 * DD + d0);
        const float4 y1 = *reinterpret_cast<const float4*>(implicit_emb + (size_t)j1 * DD + d0);
        acc.x += y0.x; acc.y += y0.y; acc.z += y0.z; acc.w += y0.w;
        acc.x += y1.x; acc.y += y1.y; acc.z += y1.z; acc.w += y1.w;
    }
    if (l < len) {
        const int j = hrow[l];
        const float4 y = *reinterpret_cast<const float4*>(implicit_emb + (size_t)j * DD + d0);
        acc.x += y.x; acc.y += y.y; acc.z += y.z; acc.w += y.w;
    }

    // Merge the wave's two parity halves (lane i and i^32 cover the same d-range).
    acc.x += __shfl_xor(acc.x, 32, 64);
    acc.y += __shfl_xor(acc.y, 32, 64);
    acc.z += __shfl_xor(acc.z, 32, 64);
    acc.w += __shfl_xor(acc.w, 32, 64);

    // Per-lane scalar partial of q . (sum y), then reduce 32 distinct lanes.
    float s = q.x * acc.x + q.y * acc.y + q.z * acc.z + q.w * acc.w;
    s += __shfl_down(s, 16, 64);
    s += __shfl_down(s, 8, 64);
    s += __shfl_down(s, 4, 64);
    s += __shfl_down(s, 2, 64);
    s += __shfl_down(s, 1, 64);

    __shared__ float partial[4];
    if (lane == 0) partial[w] = s;
    __syncthreads();

    // Wave 0 computes the explicit term q.p and combines everything.
    if (w == 0) {
        const int u = user_ids[b];
        const float4 p = *reinterpret_cast<const float4*>(user_emb + (size_t)u * DD + d0);
        float bs = p.x * q.x + p.y * q.y + p.z * q.z + p.w * q.w;
        bs += __shfl_down(bs, 16, 64);
        bs += __shfl_down(bs, 8, 64);
        bs += __shfl_down(bs, 4, 64);
        bs += __shfl_down(bs, 2, 64);
        bs += __shfl_down(bs, 1, 64);
        if (lane == 0) {
            const float S = partial[0] + partial[1] + partial[2] + partial[3];
            const float norm = (len > 0) ? rsqrtf((float)len) : 0.f;
            out[b] = global_bias[0] + user_bias[u] + item_bias[it] + bs + norm * S;
        }
    }
}

extern "C" void kernel_launch(void* const* d_in, const int* in_sizes, int n_in,
                              void* d_out, int out_size, void* d_ws, size_t ws_size,
                              hipStream_t stream) {
    const int*   user_ids     = (const int*)d_in[0];
    const int*   item_ids     = (const int*)d_in[1];
    const int*   hist_items   = (const int*)d_in[2];
    const int*   hist_len     = (const int*)d_in[3];
    const float* user_emb     = (const float*)d_in[4];
    const float* item_emb     = (const float*)d_in[5];
    const float* implicit_emb = (const float*)d_in[6];
    const float* user_bias    = (const float*)d_in[7];
    const float* item_bias    = (const float*)d_in[8];
    const float* global_bias  = (const float*)d_in[9];
    float* out = (float*)d_out;

    svdpp_kernel<<<BB, 256, 0, stream>>>(
        user_ids, item_ids, hist_items, hist_len,
        user_emb, item_emb, implicit_emb,
        user_bias, item_bias, global_bias, out);
}

// Round 3
// 47.834 us; speedup vs baseline: 1.3870x; 1.3374x over previous
//
#include <hip/hip_runtime.h>
#include <hip/hip_fp16.h>

// SVD++ scoring: out[b] = mu + b_u + b_i + q_i . (p_u + rsqrt(len)*sum_{l<len} y[hist[b][l]])
// B=8192, D=128, L=200.
//
// Round 3: the bound is the L2-miss path (~198 MB @ ~3.2 TB/s). Halve the bytes:
//   Kernel 1: implicit_emb fp32 -> fp16 into d_ws (25.6 MB), streaming.
//   Kernel 2: block-per-b gather of 256B fp16 rows; history indices staged in LDS
//             (lgkmcnt, decoupled from row vmcnt); unroll 4 -> 4 rows in flight
//             per half-wave. fp32 accumulation.
// Fallback to fp32 gather if ws_size is too small.

#define BB 8192
#define DD 128
#define LL 200

struct __align__(8) half4 { __half2 a, b; };

__global__ __launch_bounds__(256) void convert_kernel(
    const float* __restrict__ in, __half* __restrict__ out, int n8)
{
    int i = blockIdx.x * blockDim.x + threadIdx.x;   // one 8-float chunk per thread
    if (i >= n8) return;
    const float4 v0 = reinterpret_cast<const float4*>(in)[2 * i];
    const float4 v1 = reinterpret_cast<const float4*>(in)[2 * i + 1];
    half4 h0, h1;
    h0.a = __floats2half2_rn(v0.x, v0.y);
    h0.b = __floats2half2_rn(v0.z, v0.w);
    h1.a = __floats2half2_rn(v1.x, v1.y);
    h1.b = __floats2half2_rn(v1.z, v1.w);
    reinterpret_cast<half4*>(out)[2 * i]     = h0;
    reinterpret_cast<half4*>(out)[2 * i + 1] = h1;
}

__device__ __forceinline__ void acc_row(float4& acc, const half4 r) {
    const float2 lo = __half22float2(r.a);
    const float2 hi = __half22float2(r.b);
    acc.x += lo.x; acc.y += lo.y; acc.z += hi.x; acc.w += hi.y;
}

__global__ __launch_bounds__(256) void svdpp_fp16_kernel(
    const int* __restrict__ user_ids,
    const int* __restrict__ item_ids,
    const int* __restrict__ hist_items,
    const int* __restrict__ hist_len,
    const float* __restrict__ user_emb,
    const float* __restrict__ item_emb,
    const __half* __restrict__ imp16,
    const float* __restrict__ user_bias,
    const float* __restrict__ item_bias,
    const float* __restrict__ global_bias,
    float* __restrict__ out)
{
    const int b    = blockIdx.x;
    const int tid  = threadIdx.x;
    const int w    = tid >> 6;
    const int lane = tid & 63;
    const int half = lane >> 5;
    const int sub  = (w << 1) | half;     // 8 half-wave work units, stride 8
    const int d0   = (lane & 31) << 2;    // 4 elems/lane over 32 lanes = 128

    __shared__ int   hidx[LL];
    __shared__ float partial[4];

    const int len = hist_len[b];
    const int it  = item_ids[b];

    if (tid < LL) hidx[tid] = hist_items[(size_t)b * LL + tid];
    __syncthreads();

    const float4 q = *reinterpret_cast<const float4*>(item_emb + (size_t)it * DD + d0);

    float4 acc = make_float4(0.f, 0.f, 0.f, 0.f);

    int l = sub;
    for (; l + 24 < len; l += 32) {           // 4 independent rows in flight
        const int j0 = hidx[l];
        const int j1 = hidx[l + 8];
        const int j2 = hidx[l + 16];
        const int j3 = hidx[l + 24];
        const half4 r0 = *reinterpret_cast<const half4*>(imp16 + (size_t)j0 * DD + d0);
        const half4 r1 = *reinterpret_cast<const half4*>(imp16 + (size_t)j1 * DD + d0);
        const half4 r2 = *reinterpret_cast<const half4*>(imp16 + (size_t)j2 * DD + d0);
        const half4 r3 = *reinterpret_cast<const half4*>(imp16 + (size_t)j3 * DD + d0);
        acc_row(acc, r0); acc_row(acc, r1); acc_row(acc, r2); acc_row(acc, r3);
    }
    for (; l < len; l += 8) {
        const int j = hidx[l];
        const half4 r = *reinterpret_cast<const half4*>(imp16 + (size_t)j * DD + d0);
        acc_row(acc, r);
    }

    // Merge the wave's two parity halves (lane i and i^32 cover the same d-range).
    acc.x += __shfl_xor(acc.x, 32, 64);
    acc.y += __shfl_xor(acc.y, 32, 64);
    acc.z += __shfl_xor(acc.z, 32, 64);
    acc.w += __shfl_xor(acc.w, 32, 64);

    float s = q.x * acc.x + q.y * acc.y + q.z * acc.z + q.w * acc.w;
    s += __shfl_down(s, 16, 64);
    s += __shfl_down(s, 8, 64);
    s += __shfl_down(s, 4, 64);
    s += __shfl_down(s, 2, 64);
    s += __shfl_down(s, 1, 64);

    if (lane == 0) partial[w] = s;
    __syncthreads();

    if (w == 0) {
        const int u = user_ids[b];
        const float4 p = *reinterpret_cast<const float4*>(user_emb + (size_t)u * DD + d0);
        float bs = p.x * q.x + p.y * q.y + p.z * q.z + p.w * q.w;
        bs += __shfl_down(bs, 16, 64);
        bs += __shfl_down(bs, 8, 64);
        bs += __shfl_down(bs, 4, 64);
        bs += __shfl_down(bs, 2, 64);
        bs += __shfl_down(bs, 1, 64);
        if (lane == 0) {
            const float S = partial[0] + partial[1] + partial[2] + partial[3];
            const float norm = (len > 0) ? rsqrtf((float)len) : 0.f;
            out[b] = global_bias[0] + user_bias[u] + item_bias[it] + bs + norm * S;
        }
    }
}

// Fallback (R2 kernel): fp32 gather, used only if ws_size can't hold the fp16 table.
__global__ __launch_bounds__(256) void svdpp_fp32_kernel(
    const int* __restrict__ user_ids,
    const int* __restrict__ item_ids,
    const int* __restrict__ hist_items,
    const int* __restrict__ hist_len,
    const float* __restrict__ user_emb,
    const float* __restrict__ item_emb,
    const float* __restrict__ implicit_emb,
    const float* __restrict__ user_bias,
    const float* __restrict__ item_bias,
    const float* __restrict__ global_bias,
    float* __restrict__ out)
{
    const int b    = blockIdx.x;
    const int tid  = threadIdx.x;
    const int w    = tid >> 6;
    const int lane = tid & 63;
    const int half = lane >> 5;
    const int sub  = (w << 1) | half;
    const int d0   = (lane & 31) << 2;

    const int len = hist_len[b];
    const int it  = item_ids[b];
    const float4 q = *reinterpret_cast<const float4*>(item_emb + (size_t)it * DD + d0);
    const int* __restrict__ hrow = hist_items + (size_t)b * LL;

    float4 acc = make_float4(0.f, 0.f, 0.f, 0.f);
    int l = sub;
    for (; l + 8 < len; l += 16) {
        const int j0 = hrow[l];
        const int j1 = hrow[l + 8];
        const float4 y0 = *reinterpret_cast<const float4*>(implicit_emb + (size_t)j0 * DD + d0);
        const float4 y1 = *reinterpret_cast<const float4*>(implicit_emb + (size_t)j1 * DD + d0);
        acc.x += y0.x; acc.y += y0.y; acc.z += y0.z; acc.w += y0.w;
        acc.x += y1.x; acc.y += y1.y; acc.z += y1.z; acc.w += y1.w;
    }
    if (l < len) {
        const int j = hrow[l];
        const float4 y = *reinterpret_cast<const float4*>(implicit_emb + (size_t)j * DD + d0);
        acc.x += y.x; acc.y += y.y; acc.z += y.z; acc.w += y.w;
    }

    acc.x += __shfl_xor(acc.x, 32, 64);
    acc.y += __shfl_xor(acc.y, 32, 64);
    acc.z += __shfl_xor(acc.z, 32, 64);
    acc.w += __shfl_xor(acc.w, 32, 64);

    float s = q.x * acc.x + q.y * acc.y + q.z * acc.z + q.w * acc.w;
    s += __shfl_down(s, 16, 64);
    s += __shfl_down(s, 8, 64);
    s += __shfl_down(s, 4, 64);
    s += __shfl_down(s, 2, 64);
    s += __shfl_down(s, 1, 64);

    __shared__ float partial[4];
    if (lane == 0) partial[w] = s;
    __syncthreads();

    if (w == 0) {
        const int u = user_ids[b];
        const float4 p = *reinterpret_cast<const float4*>(user_emb + (size_t)u * DD + d0);
        float bs = p.x * q.x + p.y * q.y + p.z * q.z + p.w * q.w;
        bs += __shfl_down(bs, 16, 64);
        bs += __shfl_down(bs, 8, 64);
        bs += __shfl_down(bs, 4, 64);
        bs += __shfl_down(bs, 2, 64);
        bs += __shfl_down(bs, 1, 64);
        if (lane == 0) {
            const float S = partial[0] + partial[1] + partial[2] + partial[3];
            const float norm = (len > 0) ? rsqrtf((float)len) : 0.f;
            out[b] = global_bias[0] + user_bias[u] + item_bias[it] + bs + norm * S;
        }
    }
}

extern "C" void kernel_launch(void* const* d_in, const int* in_sizes, int n_in,
                              void* d_out, int out_size, void* d_ws, size_t ws_size,
                              hipStream_t stream) {
    const int*   user_ids     = (const int*)d_in[0];
    const int*   item_ids     = (const int*)d_in[1];
    const int*   hist_items   = (const int*)d_in[2];
    const int*   hist_len     = (const int*)d_in[3];
    const float* user_emb     = (const float*)d_in[4];
    const float* item_emb     = (const float*)d_in[5];
    const float* implicit_emb = (const float*)d_in[6];
    const float* user_bias    = (const float*)d_in[7];
    const float* item_bias    = (const float*)d_in[8];
    const float* global_bias  = (const float*)d_in[9];
    float* out = (float*)d_out;

    const size_t n_elems = (size_t)100000 * DD;          // 12.8M
    const size_t fp16_bytes = n_elems * sizeof(__half);  // 25.6 MB

    if (ws_size >= fp16_bytes) {
        __half* imp16 = (__half*)d_ws;
        const int n8 = (int)(n_elems / 8);               // 1.6M chunks of 8 floats
        convert_kernel<<<(n8 + 255) / 256, 256, 0, stream>>>(implicit_emb, imp16, n8);
        svdpp_fp16_kernel<<<BB, 256, 0, stream>>>(
            user_ids, item_ids, hist_items, hist_len,
            user_emb, item_emb, imp16,
            user_bias, item_bias, global_bias, out);
    } else {
        svdpp_fp32_kernel<<<BB, 256, 0, stream>>>(
            user_ids, item_ids, hist_items, hist_len,
            user_emb, item_emb, implicit_emb,
            user_bias, item_bias, global_bias, out);
    }
}